// Round 18
// baseline (354.735 us; speedup 1.0000x reference)
//
#include <hip/hip_runtime.h>
#include <math.h>

#define D_MODEL   1024
#define N_HEADS   16
#define H_DIM     64
#define SEQ       2048
#define BATCH     2
#define ROWS      (BATCH * SEQ)        // 4096
#define THREE_D   (3 * D_MODEL)       // 3072

// softmax scale: 1/sqrt(64) * log2(e)  (applied inside softmax, exp2 domain)
#define QK_SCALE  (0.125f * 1.44269504088896340736f)
// defer-max threshold: 8 in log2 domain -> raw units
#define THR_RAW   (8.0f / QK_SCALE)

typedef __attribute__((ext_vector_type(8))) short short8v;   // 8 bf16
typedef __attribute__((ext_vector_type(4))) float f32x4;
typedef __attribute__((ext_vector_type(4))) unsigned int uint4v;
typedef __attribute__((ext_vector_type(2))) unsigned int uint2v;

union Frag { uint4v u; short8v s; };

__device__ __forceinline__ void async_copy16(const void* g, void* l)
{
    __builtin_amdgcn_global_load_lds(
        (const __attribute__((address_space(1))) void*)g,
        (__attribute__((address_space(3))) void*)l,
        16, 0, 0);
}

// LDS octet swizzle key (attn)
__device__ __forceinline__ int swz8(int row, int oct)
{
    return oct ^ ((row ^ (row >> 2)) & 7);
}

__device__ __forceinline__ uint2v shfl_u2(uint2v v, int src)
{
    uint2v r;
    r.x = (unsigned)__shfl((int)v.x, src);
    r.y = (unsigned)__shfl((int)v.y, src);
    return r;
}

// split 8 floats into 2 packed bf16x8 planes (truncation)
__device__ __forceinline__ void split2x8(const float* v, uint4v& U1, uint4v& U2)
{
    unsigned b1[8], b2[8];
#pragma unroll
    for (int j = 0; j < 8; ++j) {
        const unsigned u = __float_as_uint(v[j]);
        b1[j] = u;
        const float r = v[j] - __uint_as_float(u & 0xFFFF0000u);
        b2[j] = __float_as_uint(r);
    }
    U1 = (uint4v){ (b1[0]>>16)|(b1[1]&0xFFFF0000u), (b1[2]>>16)|(b1[3]&0xFFFF0000u),
                   (b1[4]>>16)|(b1[5]&0xFFFF0000u), (b1[6]>>16)|(b1[7]&0xFFFF0000u) };
    U2 = (uint4v){ (b2[0]>>16)|(b2[1]&0xFFFF0000u), (b2[2]>>16)|(b2[3]&0xFFFF0000u),
                   (b2[4]>>16)|(b2[5]&0xFFFF0000u), (b2[6]>>16)|(b2[7]&0xFFFF0000u) };
}

// packed-plane flat formula: short_off(e) = ((e>>5)<<6) + (e&31), plane2 +32
__device__ __forceinline__ void pack_store(unsigned short* rowp, int col, float val)
{
    unsigned short* d = rowp + ((col >> 5) << 6) + (col & 31);
    const unsigned u = __float_as_uint(val);
    d[0]  = (unsigned short)(u >> 16);
    const float r = val - __uint_as_float(u & 0xFFFF0000u);
    d[32] = (unsigned short)(__float_as_uint(r) >> 16);
}

// ---------------------------------------------------------------------------
// split_pack3: all three input tensors in one launch (segmented grid).
// ---------------------------------------------------------------------------
__global__ __launch_bounds__(256)
void split_pack3(const float* __restrict__ x,    unsigned short* __restrict__ px,
                 const float* __restrict__ w1,   unsigned short* __restrict__ pw1,
                 const float* __restrict__ w2,   unsigned short* __restrict__ pw2)
{
    const int bid = blockIdx.x;
    const float* in;
    unsigned short* out;
    size_t base;
    if (bid < 2048)      { in = x;  out = px;  base = (size_t)bid * 2048; }
    else if (bid < 3584) { in = w1; out = pw1; base = (size_t)(bid - 2048) * 2048; }
    else                 { in = w2; out = pw2; base = (size_t)(bid - 3584) * 2048; }

    const size_t e0 = base + (size_t)threadIdx.x * 8;
    const float4 a0 = *reinterpret_cast<const float4*>(in + e0);
    const float4 a1 = *reinterpret_cast<const float4*>(in + e0 + 4);
    float v[8] = { a0.x, a0.y, a0.z, a0.w, a1.x, a1.y, a1.z, a1.w };
    uint4v U1, U2;
    split2x8(v, U1, U2);
    unsigned short* d = out + ((e0 >> 5) << 6) + (e0 & 31);
    *reinterpret_cast<uint4v*>(d)      = U1;
    *reinterpret_cast<uint4v*>(d + 32) = U2;
}

// ---------------------------------------------------------------------------
// RoPE cos/sin table (fp64 accuracy)
// ---------------------------------------------------------------------------
__global__ void rope_table(float* __restrict__ tab)
{
    const int idx = blockIdx.x * 256 + threadIdx.x;
    const int s = idx >> 5;
    const int i = idx & 31;
    const double inv = pow(10000.0, -(double)(2 * i) / 64.0);
    const double f = (double)s * inv;
    tab[idx * 2 + 0] = (float)cos(f);
    tab[idx * 2 + 1] = (float)sin(f);
}

// ---------------------------------------------------------------------------
// GEMM: BM=128, BN=64, BK=32.  4 waves stacked in M (wave = 32x64).
// LDS 48 KB -> 3 blocks/CU.  3 MFMA products; packed-plane inputs;
// XCD-bijective remap (gridDim.x % 8 == 0).  (unchanged from R17 — verified)
// ---------------------------------------------------------------------------

// gemm_p: fp32 C out (GEMM3)
__global__ __launch_bounds__(256, 2)
void gemm_p(const unsigned short* __restrict__ Ap, int ldA2,
            const unsigned short* __restrict__ Bp, int ldB2,
            const float* __restrict__ bias,
            float* __restrict__ C, int ldc, int K,
            int nbx, size_t segA, size_t segB, int segBias, size_t segC)
{
    __shared__ __align__(16) unsigned short As[2][128 * 64];
    __shared__ __align__(16) unsigned short Bs[2][64 * 64];

    const int fid  = blockIdx.y * gridDim.x + blockIdx.x;
    const int bxpx = gridDim.x >> 3;
    const int xcd  = fid & 7;
    const int idx  = fid >> 3;
    const int bxx  = xcd * bxpx + idx % bxpx;
    const int by   = idx / bxpx;

    const int seg = bxx / nbx;
    const int bxs = bxx - seg * nbx;
    const int bm  = by * 128;
    const int bn  = bxs * 64;
    Ap   += (size_t)seg * segA;
    Bp   += (size_t)seg * segB;
    bias += seg * segBias;
    C    += (size_t)seg * segC;

    const int t    = threadIdx.x;
    const int w    = t >> 6;
    const int lane = t & 63;
    const int cl   = lane & 15;
    const int kq   = lane >> 4;
    const int lrow = lane >> 3;
    const int gs   = lane & 7;

    auto stage = [&](int buf, int k0) {
        const int gl = gs ^ lrow;
#pragma unroll
        for (int q = 0; q < 4; ++q) {
            const int r0  = (w * 4 + q) * 8;
            async_copy16(Ap + (size_t)(bm + r0 + lrow) * ldA2 + (k0 << 1) + (gl << 3),
                         &As[buf][r0 * 64]);
        }
#pragma unroll
        for (int q = 0; q < 2; ++q) {
            const int r0  = (w * 2 + q) * 8;
            async_copy16(Bp + (size_t)(bn + r0 + lrow) * ldB2 + (k0 << 1) + (gl << 3),
                         &Bs[buf][r0 * 64]);
        }
    };

    f32x4 acc[2][4];
#pragma unroll
    for (int m = 0; m < 2; ++m)
#pragma unroll
        for (int n = 0; n < 4; ++n) acc[m][n] = (f32x4)(0.f);

    const int NT = K >> 5;
    stage(0, 0);

    for (int it = 0; it < NT; ++it) {
        __syncthreads();
        if (it + 1 < NT)
            stage((it + 1) & 1, (it + 1) << 5);

        const unsigned short* as = As[it & 1];
        const unsigned short* bs = Bs[it & 1];

        short8v A1[2], A2[2], B1[4], B2[4];
#pragma unroll
        for (int m = 0; m < 2; ++m) {
            const int r = w * 32 + m * 16 + cl;
            const unsigned short* ar = as + r * 64;
            A1[m] = *reinterpret_cast<const short8v*>(ar + (( kq      ^ (r & 7)) << 3));
            A2[m] = *reinterpret_cast<const short8v*>(ar + (((kq + 4) ^ (r & 7)) << 3));
        }
#pragma unroll
        for (int n = 0; n < 4; ++n) {
            const int r = n * 16 + cl;
            const unsigned short* br = bs + r * 64;
            B1[n] = *reinterpret_cast<const short8v*>(br + (( kq      ^ (r & 7)) << 3));
            B2[n] = *reinterpret_cast<const short8v*>(br + (((kq + 4) ^ (r & 7)) << 3));
        }

#pragma unroll
        for (int m = 0; m < 2; ++m)
#pragma unroll
            for (int n = 0; n < 4; ++n) {
                f32x4 c = acc[m][n];
                c = __builtin_amdgcn_mfma_f32_16x16x32_bf16(A1[m], B1[n], c, 0, 0, 0);
                c = __builtin_amdgcn_mfma_f32_16x16x32_bf16(A2[m], B1[n], c, 0, 0, 0);
                c = __builtin_amdgcn_mfma_f32_16x16x32_bf16(A1[m], B2[n], c, 0, 0, 0);
                acc[m][n] = c;
            }
    }

    const int rw = lane >> 4;
#pragma unroll
    for (int n = 0; n < 4; ++n) {
        const int col = bn + n * 16 + cl;
        const float bv = bias[col];
#pragma unroll
        for (int m = 0; m < 2; ++m) {
            const size_t rbase = (size_t)(bm + w * 32 + m * 16 + rw * 4);
#pragma unroll
            for (int i = 0; i < 4; ++i)
                C[(rbase + i) * ldc + col] = acc[m][n][i] + bv;
        }
    }
}

// gemm_p_pack: packed-plane C out (QKV projection -> attn consumes directly)
__global__ __launch_bounds__(256, 2)
void gemm_p_pack(const unsigned short* __restrict__ Ap, int ldA2,
                 const unsigned short* __restrict__ Bp, int ldB2,
                 const float* __restrict__ bias,
                 unsigned short* __restrict__ Cp, int ldc2, int K,
                 int nbx, size_t segA, size_t segB, int segBias, size_t segC)
{
    __shared__ __align__(16) unsigned short As[2][128 * 64];
    __shared__ __align__(16) unsigned short Bs[2][64 * 64];

    const int fid  = blockIdx.y * gridDim.x + blockIdx.x;
    const int bxpx = gridDim.x >> 3;
    const int xcd  = fid & 7;
    const int idx  = fid >> 3;
    const int bxx  = xcd * bxpx + idx % bxpx;
    const int by   = idx / bxpx;

    const int seg = bxx / nbx;
    const int bxs = bxx - seg * nbx;
    const int bm  = by * 128;
    const int bn  = bxs * 64;
    Ap   += (size_t)seg * segA;
    Bp   += (size_t)seg * segB;
    bias += seg * segBias;
    Cp   += (size_t)seg * segC;

    const int t    = threadIdx.x;
    const int w    = t >> 6;
    const int lane = t & 63;
    const int cl   = lane & 15;
    const int kq   = lane >> 4;
    const int lrow = lane >> 3;
    const int gs   = lane & 7;

    auto stage = [&](int buf, int k0) {
        const int gl = gs ^ lrow;
#pragma unroll
        for (int q = 0; q < 4; ++q) {
            const int r0  = (w * 4 + q) * 8;
            async_copy16(Ap + (size_t)(bm + r0 + lrow) * ldA2 + (k0 << 1) + (gl << 3),
                         &As[buf][r0 * 64]);
        }
#pragma unroll
        for (int q = 0; q < 2; ++q) {
            const int r0  = (w * 2 + q) * 8;
            async_copy16(Bp + (size_t)(bn + r0 + lrow) * ldB2 + (k0 << 1) + (gl << 3),
                         &Bs[buf][r0 * 64]);
        }
    };

    f32x4 acc[2][4];
#pragma unroll
    for (int m = 0; m < 2; ++m)
#pragma unroll
        for (int n = 0; n < 4; ++n) acc[m][n] = (f32x4)(0.f);

    const int NT = K >> 5;
    stage(0, 0);

    for (int it = 0; it < NT; ++it) {
        __syncthreads();
        if (it + 1 < NT)
            stage((it + 1) & 1, (it + 1) << 5);

        const unsigned short* as = As[it & 1];
        const unsigned short* bs = Bs[it & 1];

        short8v A1[2], A2[2], B1[4], B2[4];
#pragma unroll
        for (int m = 0; m < 2; ++m) {
            const int r = w * 32 + m * 16 + cl;
            const unsigned short* ar = as + r * 64;
            A1[m] = *reinterpret_cast<const short8v*>(ar + (( kq      ^ (r & 7)) << 3));
            A2[m] = *reinterpret_cast<const short8v*>(ar + (((kq + 4) ^ (r & 7)) << 3));
        }
#pragma unroll
        for (int n = 0; n < 4; ++n) {
            const int r = n * 16 + cl;
            const unsigned short* br = bs + r * 64;
            B1[n] = *reinterpret_cast<const short8v*>(br + (( kq      ^ (r & 7)) << 3));
            B2[n] = *reinterpret_cast<const short8v*>(br + (((kq + 4) ^ (r & 7)) << 3));
        }

#pragma unroll
        for (int m = 0; m < 2; ++m)
#pragma unroll
            for (int n = 0; n < 4; ++n) {
                f32x4 c = acc[m][n];
                c = __builtin_amdgcn_mfma_f32_16x16x32_bf16(A1[m], B1[n], c, 0, 0, 0);
                c = __builtin_amdgcn_mfma_f32_16x16x32_bf16(A2[m], B1[n], c, 0, 0, 0);
                c = __builtin_amdgcn_mfma_f32_16x16x32_bf16(A1[m], B2[n], c, 0, 0, 0);
                acc[m][n] = c;
            }
    }

    const int rw = lane >> 4;
#pragma unroll
    for (int n = 0; n < 4; ++n) {
        const int col = bn + n * 16 + cl;
        const float bv = bias[col];
#pragma unroll
        for (int m = 0; m < 2; ++m) {
            const size_t rbase = (size_t)(bm + w * 32 + m * 16 + rw * 4);
#pragma unroll
            for (int i = 0; i < 4; ++i)
                pack_store(Cp + (rbase + i) * (size_t)ldc2, col, acc[m][n][i] + bv);
        }
    }
}

// ---------------------------------------------------------------------------
// gemm_p_rope: GEMM1 with RoPE fused into the epilogue; writes packed planes.
// ---------------------------------------------------------------------------
__global__ __launch_bounds__(256, 2)
void gemm_p_rope(const unsigned short* __restrict__ Ap, int ldA2,
                 const unsigned short* __restrict__ Bp, int ldB2,
                 const float* __restrict__ bias,
                 const float* __restrict__ tab,
                 unsigned short* __restrict__ out, int K)
{
    __shared__ __align__(16) unsigned short As[2][128 * 64];
    __shared__ __align__(16) unsigned short Bs[2][64 * 64];

    const int fid  = blockIdx.y * gridDim.x + blockIdx.x;
    const int bxpx = gridDim.x >> 3;
    const int xcd  = fid & 7;
    const int idx  = fid >> 3;
    const int bxx  = xcd * bxpx + idx % bxpx;
    const int by   = idx / bxpx;

    const int bm  = by * 128;
    const int bn  = bxx * 64;

    const int t    = threadIdx.x;
    const int w    = t >> 6;
    const int lane = t & 63;
    const int cl   = lane & 15;
    const int kq   = lane >> 4;
    const int lrow = lane >> 3;
    const int gs   = lane & 7;

    auto stage = [&](int buf, int k0) {
        const int gl = gs ^ lrow;
#pragma unroll
        for (int q = 0; q < 4; ++q) {
            const int r0  = (w * 4 + q) * 8;
            async_copy16(Ap + (size_t)(bm + r0 + lrow) * ldA2 + (k0 << 1) + (gl << 3),
                         &As[buf][r0 * 64]);
        }
#pragma unroll
        for (int q = 0; q < 2; ++q) {
            const int r0  = (w * 2 + q) * 8;
            async_copy16(Bp + (size_t)(bn + r0 + lrow) * ldB2 + (k0 << 1) + (gl << 3),
                         &Bs[buf][r0 * 64]);
        }
    };

    f32x4 acc[2][4];
#pragma unroll
    for (int m = 0; m < 2; ++m)
#pragma unroll
        for (int n = 0; n < 4; ++n) acc[m][n] = (f32x4)(0.f);

    const int NT = K >> 5;
    stage(0, 0);

    for (int it = 0; it < NT; ++it) {
        __syncthreads();
        if (it + 1 < NT)
            stage((it + 1) & 1, (it + 1) << 5);

        const unsigned short* as = As[it & 1];
        const unsigned short* bs = Bs[it & 1];

        short8v A1[2], A2[2], B1[4], B2[4];
#pragma unroll
        for (int m = 0; m < 2; ++m) {
            const int r = w * 32 + m * 16 + cl;
            const unsigned short* ar = as + r * 64;
            A1[m] = *reinterpret_cast<const short8v*>(ar + (( kq      ^ (r & 7)) << 3));
            A2[m] = *reinterpret_cast<const short8v*>(ar + (((kq + 4) ^ (r & 7)) << 3));
        }
#pragma unroll
        for (int n = 0; n < 4; ++n) {
            const int r = n * 16 + cl;
            const unsigned short* br = bs + r * 64;
            B1[n] = *reinterpret_cast<const short8v*>(br + (( kq      ^ (r & 7)) << 3));
            B2[n] = *reinterpret_cast<const short8v*>(br + (((kq + 4) ^ (r & 7)) << 3));
        }

#pragma unroll
        for (int m = 0; m < 2; ++m)
#pragma unroll
            for (int n = 0; n < 4; ++n) {
                f32x4 c = acc[m][n];
                c = __builtin_amdgcn_mfma_f32_16x16x32_bf16(A1[m], B1[n], c, 0, 0, 0);
                c = __builtin_amdgcn_mfma_f32_16x16x32_bf16(A2[m], B1[n], c, 0, 0, 0);
                c = __builtin_amdgcn_mfma_f32_16x16x32_bf16(A1[m], B2[n], c, 0, 0, 0);
                acc[m][n] = c;
            }
    }

    // ---- epilogue: rope (q/k thirds) + packed-plane store
    const int rw = lane >> 4;
    const bool doRope = (bn < 2 * D_MODEL);
#pragma unroll
    for (int n = 0; n < 2; ++n) {
        const int colA = bn + n * 16 + cl;
        const int colB = colA + 32;
        const float bvA = bias[colA];
        const float bvB = bias[colB];
        const int d = n * 16 + cl;
#pragma unroll
        for (int m = 0; m < 2; ++m) {
            const size_t rbase = (size_t)(bm + w * 32 + m * 16 + rw * 4);
#pragma unroll
            for (int i = 0; i < 4; ++i) {
                const size_t row = rbase + i;
                const float t1 = acc[m][n][i]     + bvA;
                const float t2 = acc[m][n + 2][i] + bvB;
                float r1 = t1, r2 = t2;
                if (doRope) {
                    const int s = (int)(row & (SEQ - 1));
                    const float c  = tab[(s * 32 + d) * 2 + 0];
                    const float sn = tab[(s * 32 + d) * 2 + 1];
                    r1 = t1 * c - t2 * sn;
                    r2 = t2 * c + t1 * sn;
                }
                unsigned short* op = out + row * (size_t)(THREE_D * 2);
                pack_store(op, colA, r1);
                pack_store(op, colB, r2);
            }
        }
    }
}

// ---------------------------------------------------------------------------
// Flash attention on PACKED q/k/v planes, kv-split 2x.
// grid = (16, 32, 2): z = kv half; 1024 blocks -> 3 resident/CU (48 KB LDS)
// = 24 waves/CU.  Partials (raw acc, raw m, l) to ws; combine normalizes.
// Structure otherwise identical to R16/R17 (verified).
// ---------------------------------------------------------------------------
__global__ __launch_bounds__(512)
void attn_mfma(const unsigned short* __restrict__ Qp,
               const unsigned short* __restrict__ Kp,
               const unsigned short* __restrict__ Vp,
               float* __restrict__ Pacc, float* __restrict__ Pml)
{
    __shared__ __align__(16) short Ks1[2][64 * 64];   // 16 KB (single plane)
    __shared__ __align__(16) short Vt1[2][64 * 64];   // 16 KB
    __shared__ __align__(16) short Vt2[2][64 * 64];   // 16 KB

    const int fid  = blockIdx.y * gridDim.x + blockIdx.x;   // 0..511
    const int half = blockIdx.z;
    const int bh   = (fid & 7) * 4 + ((fid >> 3) & 3);
    const int q0   = (fid >> 5) * 128;
    const int b    = bh >> 4;
    const int h    = bh & 15;
    const size_t rowBase = (size_t)b * SEQ;
    const int hs = h * H_DIM * 2;

    const int t    = threadIdx.x;
    const int w    = t >> 6;
    const int lane = t & 63;
    const int cl   = lane & 15;
    const int g    = lane >> 4;
    const int g2   = g >> 1;
    const int srcA = cl + 32 * (g & 1);
    const int srcB = srcA + 16;

    const int krow = t >> 2;
    const int dob  = (t & 3) * 2;
    const int t2   = t - 256;
    const int vkq  = t2 >> 4;
    const int vdq  = t2 & 15;

    const int ksrc = (dob >> 2) * 64 + (dob & 3) * 8;

    Frag qf[2][2];   // [c][plane]
    {
        const unsigned short* qp =
            Qp + (rowBase + q0 + w * 16 + cl) * (size_t)(D_MODEL * 2) + hs;
#pragma unroll
        for (int c = 0; c < 2; ++c) {
            qf[c][0].u = *reinterpret_cast<const uint4v*>(qp + c * 64 + g * 8);
            qf[c][1].u = *reinterpret_cast<const uint4v*>(qp + c * 64 + 32 + g * 8);
        }
    }

    f32x4 acc[4];
#pragma unroll
    for (int s = 0; s < 4; ++s) acc[s] = (f32x4)(0.f);
    float m = -1e30f;
    float l = 0.f;

    uint4v k1a, k1b;
    uint2v vp1[4], vp2[4];

    const int kbase = half * (SEQ / 2);

    auto load_tile = [&](int k0) {
        if (w < 4) {
            const unsigned short* kp =
                Kp + (rowBase + k0 + krow) * (size_t)(D_MODEL * 2) + hs + ksrc;
            k1a = *reinterpret_cast<const uint4v*>(kp);
            k1b = *reinterpret_cast<const uint4v*>(kp + 8);
        } else {
            const unsigned short* vrow =
                Vp + (rowBase + k0 + vkq * 4) * (size_t)(D_MODEL * 2) + hs
                + (((vdq * 4) >> 5) << 6) + ((vdq * 4) & 31);
#pragma unroll
            for (int r = 0; r < 4; ++r) {
                vp1[r] = *reinterpret_cast<const uint2v*>(vrow + r * (D_MODEL * 2));
                vp2[r] = *reinterpret_cast<const uint2v*>(vrow + r * (D_MODEL * 2) + 32);
            }
        }
    };

    auto write_tile = [&](int buf) {
        if (w < 4) {
            short* kb1 = Ks1[buf] + krow * 64;
            *reinterpret_cast<uint4v*>(kb1 + swz8(krow, dob    ) * 8) = k1a;
            *reinterpret_cast<uint4v*>(kb1 + swz8(krow, dob + 1) * 8) = k1b;
        } else {
            const int lo = vkq >> 1;
            const int hf = (vkq & 1) * 4;
#pragma unroll
            for (int rr = 0; rr < 4; ++rr) {
                const int row  = 4 * vdq + rr;
                const int word = rr >> 1;
                const int sh   = (rr & 1) * 16;
                const unsigned e10 = (vp1[0][word] >> sh) & 0xFFFFu;
                const unsigned e11 = (vp1[1][word] >> sh) & 0xFFFFu;
                const unsigned e12 = (vp1[2][word] >> sh) & 0xFFFFu;
                const unsigned e13 = (vp1[3][word] >> sh) & 0xFFFFu;
                const unsigned e20 = (vp2[0][word] >> sh) & 0xFFFFu;
                const unsigned e21 = (vp2[1][word] >> sh) & 0xFFFFu;
                const unsigned e22 = (vp2[2][word] >> sh) & 0xFFFFu;
                const unsigned e23 = (vp2[3][word] >> sh) & 0xFFFFu;
                uint2v w1, w2;
                w1.x = e10 | (e11 << 16);
                w1.y = e12 | (e13 << 16);
                w2.x = e20 | (e21 << 16);
                w2.y = e22 | (e23 << 16);
                const int o = row * 64 + swz8(row, lo) * 8 + hf;
                *reinterpret_cast<uint2v*>(&Vt1[buf][o]) = w1;
                *reinterpret_cast<uint2v*>(&Vt2[buf][o]) = w2;
            }
        }
    };

    const int NT = (SEQ / 2) / 64;       // 16 tiles

    load_tile(kbase);
    write_tile(0);

    for (int it = 0; it < NT; ++it) {
        __syncthreads();
        const int bf = it & 1;
        if (it + 1 < NT)
            load_tile(kbase + (it + 1) * 64);

        f32x4 sacc[4];
#pragma unroll
        for (int ks = 0; ks < 4; ++ks) sacc[ks] = (f32x4)(0.f);

#pragma unroll
        for (int ks = 0; ks < 4; ++ks)
#pragma unroll
            for (int c = 0; c < 2; ++c) {
                const int row = ks * 16 + cl;
                const int po  = row * 64 + swz8(row, 4 * c + g) * 8;
                Frag ka1;
                ka1.s = *reinterpret_cast<const short8v*>(&Ks1[bf][po]);
                f32x4 s = sacc[ks];
                s = __builtin_amdgcn_mfma_f32_16x16x32_bf16(ka1.s, qf[c][0].s, s, 0, 0, 0);
                s = __builtin_amdgcn_mfma_f32_16x16x32_bf16(ka1.s, qf[c][1].s, s, 0, 0, 0);
                sacc[ks] = s;
            }

        float tm = -1e30f;
#pragma unroll
        for (int ks = 0; ks < 4; ++ks)
#pragma unroll
            for (int i = 0; i < 4; ++i) tm = fmaxf(tm, sacc[ks][i]);
        tm = fmaxf(tm, __shfl_xor(tm, 16));
        tm = fmaxf(tm, __shfl_xor(tm, 32));

        const bool need = !__all(tm <= m + THR_RAW);
        if (need) {
            const float mn = fmaxf(m, tm);
            const float sc = __builtin_amdgcn_exp2f((m - mn) * QK_SCALE);
            m = mn;
            l *= sc;
            float scv[4];
#pragma unroll
            for (int i = 0; i < 4; ++i) scv[i] = __shfl(sc, 4 * g + i);
#pragma unroll
            for (int s = 0; s < 4; ++s)
#pragma unroll
                for (int i = 0; i < 4; ++i) acc[s][i] *= scv[i];
        }
        const float mns = m * QK_SCALE;

        float rs = 0.f;
        uint2v P1[4];
#pragma unroll
        for (int ks = 0; ks < 4; ++ks) {
            float p[4];
            unsigned ub[4];
#pragma unroll
            for (int i = 0; i < 4; ++i) {
                p[i] = __builtin_amdgcn_exp2f(fmaf(sacc[ks][i], QK_SCALE, -mns));
                rs += p[i];
                ub[i] = __float_as_uint(p[i]);
            }
            P1[ks] = (uint2v){ (ub[0] >> 16) | (ub[1] & 0xFFFF0000u),
                               (ub[2] >> 16) | (ub[3] & 0xFFFF0000u) };
        }
        rs += __shfl_xor(rs, 16);
        rs += __shfl_xor(rs, 32);
        l += rs;

#pragma unroll
        for (int c = 0; c < 2; ++c) {
            uint2v a0 = shfl_u2(P1[2 * c],     srcA);
            uint2v a1 = shfl_u2(P1[2 * c + 1], srcA);
            uint2v b0 = shfl_u2(P1[2 * c],     srcB);
            uint2v b1 = shfl_u2(P1[2 * c + 1], srcB);
            uint2v lo = g2 ? a1 : a0;
            uint2v hi = g2 ? b1 : b0;
            Frag pa;
            pa.u = (uint4v){ lo.x, lo.y, hi.x, hi.y };
#pragma unroll
            for (int s = 0; s < 4; ++s) {
                const int row = s * 16 + cl;
                const int vo  = row * 64 + swz8(row, 4 * c + g) * 8;
                Frag vb1, vb2;
                vb1.s = *reinterpret_cast<const short8v*>(&Vt1[bf][vo]);
                vb2.s = *reinterpret_cast<const short8v*>(&Vt2[bf][vo]);
                f32x4 a = acc[s];
                a = __builtin_amdgcn_mfma_f32_16x16x32_bf16(pa.s, vb1.s, a, 0, 0, 0);
                a = __builtin_amdgcn_mfma_f32_16x16x32_bf16(pa.s, vb2.s, a, 0, 0, 0);
                acc[s] = a;
            }
        }

        if (it + 1 < NT)
            write_tile(bf ^ 1);
    }

    // ---- store partials (raw acc + raw m, l); combine normalizes
    const int pblk = half * 512 + bh * 16 + (q0 >> 7);
    float* ab = Pacc + (size_t)pblk * (128 * 64);
#pragma unroll
    for (int s = 0; s < 4; ++s)
#pragma unroll
        for (int i = 0; i < 4; ++i)
            ab[(w * 16 + 4 * g + i) * 64 + s * 16 + cl] = acc[s][i];
    if (g == 0) {
        float2 ml; ml.x = m; ml.y = l;
        reinterpret_cast<float2*>(Pml)[pblk * 128 + w * 16 + cl] = ml;
    }
}

// ---------------------------------------------------------------------------
// Combine the two kv-half partials, normalize, write packed pctx.
// ---------------------------------------------------------------------------
__global__ __launch_bounds__(256)
void attn_combine(const float* __restrict__ Pacc, const float* __restrict__ Pml,
                  unsigned short* __restrict__ pctx)
{
    const int tid = blockIdx.x * 256 + threadIdx.x;    // 0 .. ROWS*256-1
    const int col = (tid & 255) * 4;                   // 0..1020
    const int row = tid >> 8;                          // 0..4095
    const int b = row >> 11, s = row & 2047;
    const int h = col >> 6,  d = col & 63;
    const int p0 = (b * 16 + h) * 16 + (s >> 7);
    const int q  = s & 127;

    const float2 mlA = reinterpret_cast<const float2*>(Pml)[p0 * 128 + q];
    const float2 mlB = reinterpret_cast<const float2*>(Pml)[(p0 + 512) * 128 + q];
    const float4 a = *reinterpret_cast<const float4*>(
        Pacc + ((size_t)p0 * 128 + q) * 64 + d);
    const float4 c = *reinterpret_cast<const float4*>(
        Pacc + ((size_t)(p0 + 512) * 128 + q) * 64 + d);

    const float mf = fmaxf(mlA.x, mlB.x);
    const float wa = __builtin_amdgcn_exp2f((mlA.x - mf) * QK_SCALE);
    const float wb = __builtin_amdgcn_exp2f((mlB.x - mf) * QK_SCALE);
    const float inv = 1.f / (wa * mlA.y + wb * mlB.y);

    unsigned short* op = pctx + (size_t)row * (D_MODEL * 2);
    pack_store(op, col + 0, (wa * a.x + wb * c.x) * inv);
    pack_store(op, col + 1, (wa * a.y + wb * c.y) * inv);
    pack_store(op, col + 2, (wa * a.z + wb * c.z) * inv);
    pack_store(op, col + 3, (wa * a.w + wb * c.w) * inv);
}

// ---------------------------------------------------------------------------
extern "C" void kernel_launch(void* const* d_in, const int* in_sizes, int n_in,
                              void* d_out, int out_size, void* d_ws, size_t ws_size,
                              hipStream_t stream)
{
    const float* x    = (const float*)d_in[0];
    const float* Win  = (const float*)d_in[1];   // (3072, 1024)
    const float* bin  = (const float*)d_in[2];   // (3072,)
    const float* Wout = (const float*)d_in[3];   // (1024, 1024)
    const float* bout = (const float*)d_in[4];   // (1024,)
    float* out = (float*)d_out;

    float* R1 = (float*)d_ws;
    float* R2 = R1 + (size_t)ROWS * THREE_D;
    unsigned short* pW  = (unsigned short*)(R2 + (size_t)ROWS * THREE_D);
    unsigned short* pWo = pW + (size_t)THREE_D * D_MODEL * 2;
    float* tab = (float*)(pWo + (size_t)D_MODEL * D_MODEL * 2);
    float* Pml = tab + (size_t)SEQ * 64;                  // 1024*128*2 floats

    unsigned short* px    = (unsigned short*)R1;   // dead once qkvp written
    unsigned short* qkvp  = (unsigned short*)R1;   // packed q/k/v (3 segments)
    unsigned short* pcomb = (unsigned short*)R2;
    unsigned short* pctx  = (unsigned short*)R2;   // overwrites pcomb (dead)
    // Pacc (1024*128*64 fp32 = 8.39M floats) in R2 tail behind pctx (4.19M):
    float* Pacc = R2 + (size_t)ROWS * D_MODEL;     // = R2 + 4.19M floats

    unsigned short* Qp = qkvp;
    unsigned short* Kp = qkvp + (size_t)ROWS * D_MODEL * 2;
    unsigned short* Vp = Kp  + (size_t)ROWS * D_MODEL * 2;

    const dim3 blk(256);

    rope_table<<<dim3(SEQ * 32 / 256), blk, 0, stream>>>(tab);

    // pack inputs/weights to bf16 planes (one fused launch)
    split_pack3<<<dim3(4096), blk, 0, stream>>>(x, px, Win, pW, Wout, pWo);

    // GEMM1 + fused rope: pcomb = pack(rope(x @ Win^T + bin))
    gemm_p_rope<<<dim3(48, 32), blk, 0, stream>>>(
        px, D_MODEL * 2, pW, D_MODEL * 2, bin, tab, pcomb, D_MODEL);

    // fused q/k/v second projection -> PACKED planes (overwrites px; dead)
    gemm_p_pack<<<dim3(48, 32), blk, 0, stream>>>(
        pcomb, THREE_D * 2, pW, D_MODEL * 2, bin, qkvp, D_MODEL * 2, D_MODEL,
        16, (size_t)(D_MODEL * 2), (size_t)D_MODEL * D_MODEL * 2, D_MODEL,
        (size_t)ROWS * D_MODEL * 2);

    // attention partials (kv-split 2x) then combine -> pctx
    attn_mfma<<<dim3(16, 32, 2), dim3(512), 0, stream>>>(
        Qp, Kp, Vp, Pacc, Pml);
    attn_combine<<<dim3(ROWS), blk, 0, stream>>>(Pacc, Pml, pctx);

    // GEMM3: out = ctx @ Wout^T + bout
    gemm_p<<<dim3(16, 32), blk, 0, stream>>>(
        pctx, D_MODEL * 2, pWo, D_MODEL * 2, bout, out, D_MODEL, D_MODEL,
        16, (size_t)0, (size_t)0, 0, (size_t)0);
}

// Round 19
// 299.291 us; speedup vs baseline: 1.1853x; 1.1853x over previous
//
#include <hip/hip_runtime.h>
#include <math.h>

#define D_MODEL   1024
#define N_HEADS   16
#define H_DIM     64
#define SEQ       2048
#define BATCH     2
#define ROWS      (BATCH * SEQ)        // 4096
#define THREE_D   (3 * D_MODEL)       // 3072

// softmax scale: 1/sqrt(64) * log2(e)  (applied inside softmax, exp2 domain)
#define QK_SCALE  (0.125f * 1.44269504088896340736f)
// defer-max threshold: 8 in log2 domain -> raw units
#define THR_RAW   (8.0f / QK_SCALE)

typedef __attribute__((ext_vector_type(8))) short short8v;   // 8 bf16
typedef __attribute__((ext_vector_type(4))) float f32x4;
typedef __attribute__((ext_vector_type(4))) unsigned int uint4v;
typedef __attribute__((ext_vector_type(2))) unsigned int uint2v;

union Frag { uint4v u; short8v s; };

__device__ __forceinline__ void async_copy16(const void* g, void* l)
{
    __builtin_amdgcn_global_load_lds(
        (const __attribute__((address_space(1))) void*)g,
        (__attribute__((address_space(3))) void*)l,
        16, 0, 0);
}

// LDS octet swizzle key (attn)
__device__ __forceinline__ int swz8(int row, int oct)
{
    return oct ^ ((row ^ (row >> 2)) & 7);
}

__device__ __forceinline__ uint2v shfl_u2(uint2v v, int src)
{
    uint2v r;
    r.x = (unsigned)__shfl((int)v.x, src);
    r.y = (unsigned)__shfl((int)v.y, src);
    return r;
}

// split 8 floats into 2 packed bf16x8 planes (truncation)
__device__ __forceinline__ void split2x8(const float* v, uint4v& U1, uint4v& U2)
{
    unsigned b1[8], b2[8];
#pragma unroll
    for (int j = 0; j < 8; ++j) {
        const unsigned u = __float_as_uint(v[j]);
        b1[j] = u;
        const float r = v[j] - __uint_as_float(u & 0xFFFF0000u);
        b2[j] = __float_as_uint(r);
    }
    U1 = (uint4v){ (b1[0]>>16)|(b1[1]&0xFFFF0000u), (b1[2]>>16)|(b1[3]&0xFFFF0000u),
                   (b1[4]>>16)|(b1[5]&0xFFFF0000u), (b1[6]>>16)|(b1[7]&0xFFFF0000u) };
    U2 = (uint4v){ (b2[0]>>16)|(b2[1]&0xFFFF0000u), (b2[2]>>16)|(b2[3]&0xFFFF0000u),
                   (b2[4]>>16)|(b2[5]&0xFFFF0000u), (b2[6]>>16)|(b2[7]&0xFFFF0000u) };
}

// packed-plane flat formula: short_off(e) = ((e>>5)<<6) + (e&31), plane2 +32
__device__ __forceinline__ void pack_store(unsigned short* rowp, int col, float val)
{
    unsigned short* d = rowp + ((col >> 5) << 6) + (col & 31);
    const unsigned u = __float_as_uint(val);
    d[0]  = (unsigned short)(u >> 16);
    const float r = val - __uint_as_float(u & 0xFFFF0000u);
    d[32] = (unsigned short)(__float_as_uint(r) >> 16);
}

// ---------------------------------------------------------------------------
// split_pack3: all three input tensors in one launch (segmented grid).
// ---------------------------------------------------------------------------
__global__ __launch_bounds__(256)
void split_pack3(const float* __restrict__ x,    unsigned short* __restrict__ px,
                 const float* __restrict__ w1,   unsigned short* __restrict__ pw1,
                 const float* __restrict__ w2,   unsigned short* __restrict__ pw2)
{
    const int bid = blockIdx.x;
    const float* in;
    unsigned short* out;
    size_t base;
    if (bid < 2048)      { in = x;  out = px;  base = (size_t)bid * 2048; }
    else if (bid < 3584) { in = w1; out = pw1; base = (size_t)(bid - 2048) * 2048; }
    else                 { in = w2; out = pw2; base = (size_t)(bid - 3584) * 2048; }

    const size_t e0 = base + (size_t)threadIdx.x * 8;
    const float4 a0 = *reinterpret_cast<const float4*>(in + e0);
    const float4 a1 = *reinterpret_cast<const float4*>(in + e0 + 4);
    float v[8] = { a0.x, a0.y, a0.z, a0.w, a1.x, a1.y, a1.z, a1.w };
    uint4v U1, U2;
    split2x8(v, U1, U2);
    unsigned short* d = out + ((e0 >> 5) << 6) + (e0 & 31);
    *reinterpret_cast<uint4v*>(d)      = U1;
    *reinterpret_cast<uint4v*>(d + 32) = U2;
}

// ---------------------------------------------------------------------------
// RoPE cos/sin table (fp64 accuracy)
// ---------------------------------------------------------------------------
__global__ void rope_table(float* __restrict__ tab)
{
    const int idx = blockIdx.x * 256 + threadIdx.x;
    const int s = idx >> 5;
    const int i = idx & 31;
    const double inv = pow(10000.0, -(double)(2 * i) / 64.0);
    const double f = (double)s * inv;
    tab[idx * 2 + 0] = (float)cos(f);
    tab[idx * 2 + 1] = (float)sin(f);
}

// ---------------------------------------------------------------------------
// GEMM: BM=128, BN=64, BK=32.  4 waves stacked in M (wave = 32x64).
// LDS 48 KB -> 3 blocks/CU.  3 MFMA products; packed-plane inputs;
// XCD-bijective remap (gridDim.x % 8 == 0).  (R17 — verified)
// ---------------------------------------------------------------------------

// gemm_p: fp32 C out (GEMM3)
__global__ __launch_bounds__(256, 2)
void gemm_p(const unsigned short* __restrict__ Ap, int ldA2,
            const unsigned short* __restrict__ Bp, int ldB2,
            const float* __restrict__ bias,
            float* __restrict__ C, int ldc, int K,
            int nbx, size_t segA, size_t segB, int segBias, size_t segC)
{
    __shared__ __align__(16) unsigned short As[2][128 * 64];
    __shared__ __align__(16) unsigned short Bs[2][64 * 64];

    const int fid  = blockIdx.y * gridDim.x + blockIdx.x;
    const int bxpx = gridDim.x >> 3;
    const int xcd  = fid & 7;
    const int idx  = fid >> 3;
    const int bxx  = xcd * bxpx + idx % bxpx;
    const int by   = idx / bxpx;

    const int seg = bxx / nbx;
    const int bxs = bxx - seg * nbx;
    const int bm  = by * 128;
    const int bn  = bxs * 64;
    Ap   += (size_t)seg * segA;
    Bp   += (size_t)seg * segB;
    bias += seg * segBias;
    C    += (size_t)seg * segC;

    const int t    = threadIdx.x;
    const int w    = t >> 6;
    const int lane = t & 63;
    const int cl   = lane & 15;
    const int kq   = lane >> 4;
    const int lrow = lane >> 3;
    const int gs   = lane & 7;

    auto stage = [&](int buf, int k0) {
        const int gl = gs ^ lrow;
#pragma unroll
        for (int q = 0; q < 4; ++q) {
            const int r0  = (w * 4 + q) * 8;
            async_copy16(Ap + (size_t)(bm + r0 + lrow) * ldA2 + (k0 << 1) + (gl << 3),
                         &As[buf][r0 * 64]);
        }
#pragma unroll
        for (int q = 0; q < 2; ++q) {
            const int r0  = (w * 2 + q) * 8;
            async_copy16(Bp + (size_t)(bn + r0 + lrow) * ldB2 + (k0 << 1) + (gl << 3),
                         &Bs[buf][r0 * 64]);
        }
    };

    f32x4 acc[2][4];
#pragma unroll
    for (int m = 0; m < 2; ++m)
#pragma unroll
        for (int n = 0; n < 4; ++n) acc[m][n] = (f32x4)(0.f);

    const int NT = K >> 5;
    stage(0, 0);

    for (int it = 0; it < NT; ++it) {
        __syncthreads();
        if (it + 1 < NT)
            stage((it + 1) & 1, (it + 1) << 5);

        const unsigned short* as = As[it & 1];
        const unsigned short* bs = Bs[it & 1];

        short8v A1[2], A2[2], B1[4], B2[4];
#pragma unroll
        for (int m = 0; m < 2; ++m) {
            const int r = w * 32 + m * 16 + cl;
            const unsigned short* ar = as + r * 64;
            A1[m] = *reinterpret_cast<const short8v*>(ar + (( kq      ^ (r & 7)) << 3));
            A2[m] = *reinterpret_cast<const short8v*>(ar + (((kq + 4) ^ (r & 7)) << 3));
        }
#pragma unroll
        for (int n = 0; n < 4; ++n) {
            const int r = n * 16 + cl;
            const unsigned short* br = bs + r * 64;
            B1[n] = *reinterpret_cast<const short8v*>(br + (( kq      ^ (r & 7)) << 3));
            B2[n] = *reinterpret_cast<const short8v*>(br + (((kq + 4) ^ (r & 7)) << 3));
        }

#pragma unroll
        for (int m = 0; m < 2; ++m)
#pragma unroll
            for (int n = 0; n < 4; ++n) {
                f32x4 c = acc[m][n];
                c = __builtin_amdgcn_mfma_f32_16x16x32_bf16(A1[m], B1[n], c, 0, 0, 0);
                c = __builtin_amdgcn_mfma_f32_16x16x32_bf16(A2[m], B1[n], c, 0, 0, 0);
                c = __builtin_amdgcn_mfma_f32_16x16x32_bf16(A1[m], B2[n], c, 0, 0, 0);
                acc[m][n] = c;
            }
    }

    const int rw = lane >> 4;
#pragma unroll
    for (int n = 0; n < 4; ++n) {
        const int col = bn + n * 16 + cl;
        const float bv = bias[col];
#pragma unroll
        for (int m = 0; m < 2; ++m) {
            const size_t rbase = (size_t)(bm + w * 32 + m * 16 + rw * 4);
#pragma unroll
            for (int i = 0; i < 4; ++i)
                C[(rbase + i) * ldc + col] = acc[m][n][i] + bv;
        }
    }
}

// gemm_p_pack: packed-plane C out (QKV projection -> attn consumes directly)
__global__ __launch_bounds__(256, 2)
void gemm_p_pack(const unsigned short* __restrict__ Ap, int ldA2,
                 const unsigned short* __restrict__ Bp, int ldB2,
                 const float* __restrict__ bias,
                 unsigned short* __restrict__ Cp, int ldc2, int K,
                 int nbx, size_t segA, size_t segB, int segBias, size_t segC)
{
    __shared__ __align__(16) unsigned short As[2][128 * 64];
    __shared__ __align__(16) unsigned short Bs[2][64 * 64];

    const int fid  = blockIdx.y * gridDim.x + blockIdx.x;
    const int bxpx = gridDim.x >> 3;
    const int xcd  = fid & 7;
    const int idx  = fid >> 3;
    const int bxx  = xcd * bxpx + idx % bxpx;
    const int by   = idx / bxpx;

    const int seg = bxx / nbx;
    const int bxs = bxx - seg * nbx;
    const int bm  = by * 128;
    const int bn  = bxs * 64;
    Ap   += (size_t)seg * segA;
    Bp   += (size_t)seg * segB;
    bias += seg * segBias;
    Cp   += (size_t)seg * segC;

    const int t    = threadIdx.x;
    const int w    = t >> 6;
    const int lane = t & 63;
    const int cl   = lane & 15;
    const int kq   = lane >> 4;
    const int lrow = lane >> 3;
    const int gs   = lane & 7;

    auto stage = [&](int buf, int k0) {
        const int gl = gs ^ lrow;
#pragma unroll
        for (int q = 0; q < 4; ++q) {
            const int r0  = (w * 4 + q) * 8;
            async_copy16(Ap + (size_t)(bm + r0 + lrow) * ldA2 + (k0 << 1) + (gl << 3),
                         &As[buf][r0 * 64]);
        }
#pragma unroll
        for (int q = 0; q < 2; ++q) {
            const int r0  = (w * 2 + q) * 8;
            async_copy16(Bp + (size_t)(bn + r0 + lrow) * ldB2 + (k0 << 1) + (gl << 3),
                         &Bs[buf][r0 * 64]);
        }
    };

    f32x4 acc[2][4];
#pragma unroll
    for (int m = 0; m < 2; ++m)
#pragma unroll
        for (int n = 0; n < 4; ++n) acc[m][n] = (f32x4)(0.f);

    const int NT = K >> 5;
    stage(0, 0);

    for (int it = 0; it < NT; ++it) {
        __syncthreads();
        if (it + 1 < NT)
            stage((it + 1) & 1, (it + 1) << 5);

        const unsigned short* as = As[it & 1];
        const unsigned short* bs = Bs[it & 1];

        short8v A1[2], A2[2], B1[4], B2[4];
#pragma unroll
        for (int m = 0; m < 2; ++m) {
            const int r = w * 32 + m * 16 + cl;
            const unsigned short* ar = as + r * 64;
            A1[m] = *reinterpret_cast<const short8v*>(ar + (( kq      ^ (r & 7)) << 3));
            A2[m] = *reinterpret_cast<const short8v*>(ar + (((kq + 4) ^ (r & 7)) << 3));
        }
#pragma unroll
        for (int n = 0; n < 4; ++n) {
            const int r = n * 16 + cl;
            const unsigned short* br = bs + r * 64;
            B1[n] = *reinterpret_cast<const short8v*>(br + (( kq      ^ (r & 7)) << 3));
            B2[n] = *reinterpret_cast<const short8v*>(br + (((kq + 4) ^ (r & 7)) << 3));
        }

#pragma unroll
        for (int m = 0; m < 2; ++m)
#pragma unroll
            for (int n = 0; n < 4; ++n) {
                f32x4 c = acc[m][n];
                c = __builtin_amdgcn_mfma_f32_16x16x32_bf16(A1[m], B1[n], c, 0, 0, 0);
                c = __builtin_amdgcn_mfma_f32_16x16x32_bf16(A2[m], B1[n], c, 0, 0, 0);
                c = __builtin_amdgcn_mfma_f32_16x16x32_bf16(A1[m], B2[n], c, 0, 0, 0);
                acc[m][n] = c;
            }
    }

    const int rw = lane >> 4;
#pragma unroll
    for (int n = 0; n < 4; ++n) {
        const int col = bn + n * 16 + cl;
        const float bv = bias[col];
#pragma unroll
        for (int m = 0; m < 2; ++m) {
            const size_t rbase = (size_t)(bm + w * 32 + m * 16 + rw * 4);
#pragma unroll
            for (int i = 0; i < 4; ++i)
                pack_store(Cp + (rbase + i) * (size_t)ldc2, col, acc[m][n][i] + bv);
        }
    }
}

// ---------------------------------------------------------------------------
// gemm_p_rope: GEMM1 with RoPE fused into the epilogue; writes packed planes.
// ---------------------------------------------------------------------------
__global__ __launch_bounds__(256, 2)
void gemm_p_rope(const unsigned short* __restrict__ Ap, int ldA2,
                 const unsigned short* __restrict__ Bp, int ldB2,
                 const float* __restrict__ bias,
                 const float* __restrict__ tab,
                 unsigned short* __restrict__ out, int K)
{
    __shared__ __align__(16) unsigned short As[2][128 * 64];
    __shared__ __align__(16) unsigned short Bs[2][64 * 64];

    const int fid  = blockIdx.y * gridDim.x + blockIdx.x;
    const int bxpx = gridDim.x >> 3;
    const int xcd  = fid & 7;
    const int idx  = fid >> 3;
    const int bxx  = xcd * bxpx + idx % bxpx;
    const int by   = idx / bxpx;

    const int bm  = by * 128;
    const int bn  = bxx * 64;

    const int t    = threadIdx.x;
    const int w    = t >> 6;
    const int lane = t & 63;
    const int cl   = lane & 15;
    const int kq   = lane >> 4;
    const int lrow = lane >> 3;
    const int gs   = lane & 7;

    auto stage = [&](int buf, int k0) {
        const int gl = gs ^ lrow;
#pragma unroll
        for (int q = 0; q < 4; ++q) {
            const int r0  = (w * 4 + q) * 8;
            async_copy16(Ap + (size_t)(bm + r0 + lrow) * ldA2 + (k0 << 1) + (gl << 3),
                         &As[buf][r0 * 64]);
        }
#pragma unroll
        for (int q = 0; q < 2; ++q) {
            const int r0  = (w * 2 + q) * 8;
            async_copy16(Bp + (size_t)(bn + r0 + lrow) * ldB2 + (k0 << 1) + (gl << 3),
                         &Bs[buf][r0 * 64]);
        }
    };

    f32x4 acc[2][4];
#pragma unroll
    for (int m = 0; m < 2; ++m)
#pragma unroll
        for (int n = 0; n < 4; ++n) acc[m][n] = (f32x4)(0.f);

    const int NT = K >> 5;
    stage(0, 0);

    for (int it = 0; it < NT; ++it) {
        __syncthreads();
        if (it + 1 < NT)
            stage((it + 1) & 1, (it + 1) << 5);

        const unsigned short* as = As[it & 1];
        const unsigned short* bs = Bs[it & 1];

        short8v A1[2], A2[2], B1[4], B2[4];
#pragma unroll
        for (int m = 0; m < 2; ++m) {
            const int r = w * 32 + m * 16 + cl;
            const unsigned short* ar = as + r * 64;
            A1[m] = *reinterpret_cast<const short8v*>(ar + (( kq      ^ (r & 7)) << 3));
            A2[m] = *reinterpret_cast<const short8v*>(ar + (((kq + 4) ^ (r & 7)) << 3));
        }
#pragma unroll
        for (int n = 0; n < 4; ++n) {
            const int r = n * 16 + cl;
            const unsigned short* br = bs + r * 64;
            B1[n] = *reinterpret_cast<const short8v*>(br + (( kq      ^ (r & 7)) << 3));
            B2[n] = *reinterpret_cast<const short8v*>(br + (((kq + 4) ^ (r & 7)) << 3));
        }

#pragma unroll
        for (int m = 0; m < 2; ++m)
#pragma unroll
            for (int n = 0; n < 4; ++n) {
                f32x4 c = acc[m][n];
                c = __builtin_amdgcn_mfma_f32_16x16x32_bf16(A1[m], B1[n], c, 0, 0, 0);
                c = __builtin_amdgcn_mfma_f32_16x16x32_bf16(A2[m], B1[n], c, 0, 0, 0);
                c = __builtin_amdgcn_mfma_f32_16x16x32_bf16(A1[m], B2[n], c, 0, 0, 0);
                acc[m][n] = c;
            }
    }

    // ---- epilogue: rope (q/k thirds) + packed-plane store
    const int rw = lane >> 4;
    const bool doRope = (bn < 2 * D_MODEL);
#pragma unroll
    for (int n = 0; n < 2; ++n) {
        const int colA = bn + n * 16 + cl;
        const int colB = colA + 32;
        const float bvA = bias[colA];
        const float bvB = bias[colB];
        const int d = n * 16 + cl;
#pragma unroll
        for (int m = 0; m < 2; ++m) {
            const size_t rbase = (size_t)(bm + w * 32 + m * 16 + rw * 4);
#pragma unroll
            for (int i = 0; i < 4; ++i) {
                const size_t row = rbase + i;
                const float t1 = acc[m][n][i]     + bvA;
                const float t2 = acc[m][n + 2][i] + bvB;
                float r1 = t1, r2 = t2;
                if (doRope) {
                    const int s = (int)(row & (SEQ - 1));
                    const float c  = tab[(s * 32 + d) * 2 + 0];
                    const float sn = tab[(s * 32 + d) * 2 + 1];
                    r1 = t1 * c - t2 * sn;
                    r2 = t2 * c + t1 * sn;
                }
                unsigned short* op = out + row * (size_t)(THREE_D * 2);
                pack_store(op, colA, r1);
                pack_store(op, colB, r2);
            }
        }
    }
}

// ---------------------------------------------------------------------------
// Flash attention on PACKED q/k/v planes (R17 structure) + T5 setprio
// around the MFMA clusters (8 waves with role-split staging = the regime
// where setprio measured positive).
// ---------------------------------------------------------------------------
__global__ __launch_bounds__(512)
void attn_mfma(const unsigned short* __restrict__ Qp,
               const unsigned short* __restrict__ Kp,
               const unsigned short* __restrict__ Vp,
               unsigned short* __restrict__ pctx)
{
    __shared__ __align__(16) short Ks1[2][64 * 64];   // 16 KB (single plane)
    __shared__ __align__(16) short Vt1[2][64 * 64];   // 16 KB
    __shared__ __align__(16) short Vt2[2][64 * 64];   // 16 KB

    const int fid = blockIdx.y * gridDim.x + blockIdx.x;   // 0..511
    const int bh  = (fid & 7) * 4 + ((fid >> 3) & 3);
    const int q0  = (fid >> 5) * 128;
    const int b   = bh >> 4;
    const int h   = bh & 15;
    const size_t rowBase = (size_t)b * SEQ;
    const int hs = h * H_DIM * 2;

    const int t    = threadIdx.x;
    const int w    = t >> 6;
    const int lane = t & 63;
    const int cl   = lane & 15;
    const int g    = lane >> 4;
    const int g2   = g >> 1;
    const int srcA = cl + 32 * (g & 1);
    const int srcB = srcA + 16;

    const int krow = t >> 2;
    const int dob  = (t & 3) * 2;
    const int t2   = t - 256;
    const int vkq  = t2 >> 4;
    const int vdq  = t2 & 15;

    const int ksrc = (dob >> 2) * 64 + (dob & 3) * 8;

    Frag qf[2][2];   // [c][plane]
    {
        const unsigned short* qp =
            Qp + (rowBase + q0 + w * 16 + cl) * (size_t)(D_MODEL * 2) + hs;
#pragma unroll
        for (int c = 0; c < 2; ++c) {
            qf[c][0].u = *reinterpret_cast<const uint4v*>(qp + c * 64 + g * 8);
            qf[c][1].u = *reinterpret_cast<const uint4v*>(qp + c * 64 + 32 + g * 8);
        }
    }

    f32x4 acc[4];
#pragma unroll
    for (int s = 0; s < 4; ++s) acc[s] = (f32x4)(0.f);
    float m = -1e30f;
    float l = 0.f;

    uint4v k1a, k1b;
    uint2v vp1[4], vp2[4];

    auto load_tile = [&](int k0) {
        if (w < 4) {
            const unsigned short* kp =
                Kp + (rowBase + k0 + krow) * (size_t)(D_MODEL * 2) + hs + ksrc;
            k1a = *reinterpret_cast<const uint4v*>(kp);
            k1b = *reinterpret_cast<const uint4v*>(kp + 8);
        } else {
            const unsigned short* vrow =
                Vp + (rowBase + k0 + vkq * 4) * (size_t)(D_MODEL * 2) + hs
                + (((vdq * 4) >> 5) << 6) + ((vdq * 4) & 31);
#pragma unroll
            for (int r = 0; r < 4; ++r) {
                vp1[r] = *reinterpret_cast<const uint2v*>(vrow + r * (D_MODEL * 2));
                vp2[r] = *reinterpret_cast<const uint2v*>(vrow + r * (D_MODEL * 2) + 32);
            }
        }
    };

    auto write_tile = [&](int buf) {
        if (w < 4) {
            short* kb1 = Ks1[buf] + krow * 64;
            *reinterpret_cast<uint4v*>(kb1 + swz8(krow, dob    ) * 8) = k1a;
            *reinterpret_cast<uint4v*>(kb1 + swz8(krow, dob + 1) * 8) = k1b;
        } else {
            const int lo = vkq >> 1;
            const int hf = (vkq & 1) * 4;
#pragma unroll
            for (int rr = 0; rr < 4; ++rr) {
                const int row  = 4 * vdq + rr;
                const int word = rr >> 1;
                const int sh   = (rr & 1) * 16;
                const unsigned e10 = (vp1[0][word] >> sh) & 0xFFFFu;
                const unsigned e11 = (vp1[1][word] >> sh) & 0xFFFFu;
                const unsigned e12 = (vp1[2][word] >> sh) & 0xFFFFu;
                const unsigned e13 = (vp1[3][word] >> sh) & 0xFFFFu;
                const unsigned e20 = (vp2[0][word] >> sh) & 0xFFFFu;
                const unsigned e21 = (vp2[1][word] >> sh) & 0xFFFFu;
                const unsigned e22 = (vp2[2][word] >> sh) & 0xFFFFu;
                const unsigned e23 = (vp2[3][word] >> sh) & 0xFFFFu;
                uint2v w1, w2;
                w1.x = e10 | (e11 << 16);
                w1.y = e12 | (e13 << 16);
                w2.x = e20 | (e21 << 16);
                w2.y = e22 | (e23 << 16);
                const int o = row * 64 + swz8(row, lo) * 8 + hf;
                *reinterpret_cast<uint2v*>(&Vt1[buf][o]) = w1;
                *reinterpret_cast<uint2v*>(&Vt2[buf][o]) = w2;
            }
        }
    };

    const int NT = SEQ / 64;

    load_tile(0);
    write_tile(0);

    for (int it = 0; it < NT; ++it) {
        __syncthreads();
        const int bf = it & 1;
        if (it + 1 < NT)
            load_tile((it + 1) * 64);

        f32x4 sacc[4];
#pragma unroll
        for (int ks = 0; ks < 4; ++ks) sacc[ks] = (f32x4)(0.f);

        __builtin_amdgcn_s_setprio(1);
#pragma unroll
        for (int ks = 0; ks < 4; ++ks)
#pragma unroll
            for (int c = 0; c < 2; ++c) {
                const int row = ks * 16 + cl;
                const int po  = row * 64 + swz8(row, 4 * c + g) * 8;
                Frag ka1;
                ka1.s = *reinterpret_cast<const short8v*>(&Ks1[bf][po]);
                f32x4 s = sacc[ks];
                s = __builtin_amdgcn_mfma_f32_16x16x32_bf16(ka1.s, qf[c][0].s, s, 0, 0, 0);
                s = __builtin_amdgcn_mfma_f32_16x16x32_bf16(ka1.s, qf[c][1].s, s, 0, 0, 0);
                sacc[ks] = s;
            }
        __builtin_amdgcn_s_setprio(0);

        float tm = -1e30f;
#pragma unroll
        for (int ks = 0; ks < 4; ++ks)
#pragma unroll
            for (int i = 0; i < 4; ++i) tm = fmaxf(tm, sacc[ks][i]);
        tm = fmaxf(tm, __shfl_xor(tm, 16));
        tm = fmaxf(tm, __shfl_xor(tm, 32));

        const bool need = !__all(tm <= m + THR_RAW);
        if (need) {
            const float mn = fmaxf(m, tm);
            const float sc = __builtin_amdgcn_exp2f((m - mn) * QK_SCALE);
            m = mn;
            l *= sc;
            float scv[4];
#pragma unroll
            for (int i = 0; i < 4; ++i) scv[i] = __shfl(sc, 4 * g + i);
#pragma unroll
            for (int s = 0; s < 4; ++s)
#pragma unroll
                for (int i = 0; i < 4; ++i) acc[s][i] *= scv[i];
        }
        const float mns = m * QK_SCALE;

        float rs = 0.f;
        uint2v P1[4];
#pragma unroll
        for (int ks = 0; ks < 4; ++ks) {
            float p[4];
            unsigned ub[4];
#pragma unroll
            for (int i = 0; i < 4; ++i) {
                p[i] = __builtin_amdgcn_exp2f(fmaf(sacc[ks][i], QK_SCALE, -mns));
                rs += p[i];
                ub[i] = __float_as_uint(p[i]);
            }
            P1[ks] = (uint2v){ (ub[0] >> 16) | (ub[1] & 0xFFFF0000u),
                               (ub[2] >> 16) | (ub[3] & 0xFFFF0000u) };
        }
        rs += __shfl_xor(rs, 16);
        rs += __shfl_xor(rs, 32);
        l += rs;

#pragma unroll
        for (int c = 0; c < 2; ++c) {
            uint2v a0 = shfl_u2(P1[2 * c],     srcA);
            uint2v a1 = shfl_u2(P1[2 * c + 1], srcA);
            uint2v b0 = shfl_u2(P1[2 * c],     srcB);
            uint2v b1 = shfl_u2(P1[2 * c + 1], srcB);
            uint2v lo = g2 ? a1 : a0;
            uint2v hi = g2 ? b1 : b0;
            Frag pa;
            pa.u = (uint4v){ lo.x, lo.y, hi.x, hi.y };
            __builtin_amdgcn_s_setprio(1);
#pragma unroll
            for (int s = 0; s < 4; ++s) {
                const int row = s * 16 + cl;
                const int vo  = row * 64 + swz8(row, 4 * c + g) * 8;
                Frag vb1, vb2;
                vb1.s = *reinterpret_cast<const short8v*>(&Vt1[bf][vo]);
                vb2.s = *reinterpret_cast<const short8v*>(&Vt2[bf][vo]);
                f32x4 a = acc[s];
                a = __builtin_amdgcn_mfma_f32_16x16x32_bf16(pa.s, vb1.s, a, 0, 0, 0);
                a = __builtin_amdgcn_mfma_f32_16x16x32_bf16(pa.s, vb2.s, a, 0, 0, 0);
                acc[s] = a;
            }
            __builtin_amdgcn_s_setprio(0);
        }

        if (it + 1 < NT)
            write_tile(bf ^ 1);
    }

    const float inv = 1.f / l;
    float iv[4];
#pragma unroll
    for (int i = 0; i < 4; ++i) iv[i] = __shfl(inv, 4 * g + i);
#pragma unroll
    for (int s = 0; s < 4; ++s)
#pragma unroll
        for (int i = 0; i < 4; ++i) {
            const float val = acc[s][i] * iv[i];
            const size_t grow = rowBase + q0 + w * 16 + 4 * g + i;
            const int gc = h * H_DIM + s * 16 + cl;
            pack_store(pctx + grow * (size_t)(D_MODEL * 2), gc, val);
        }
}

// ---------------------------------------------------------------------------
extern "C" void kernel_launch(void* const* d_in, const int* in_sizes, int n_in,
                              void* d_out, int out_size, void* d_ws, size_t ws_size,
                              hipStream_t stream)
{
    const float* x    = (const float*)d_in[0];
    const float* Win  = (const float*)d_in[1];   // (3072, 1024)
    const float* bin  = (const float*)d_in[2];   // (3072,)
    const float* Wout = (const float*)d_in[3];   // (1024, 1024)
    const float* bout = (const float*)d_in[4];   // (1024,)
    float* out = (float*)d_out;

    float* R1 = (float*)d_ws;
    float* R2 = R1 + (size_t)ROWS * THREE_D;
    unsigned short* pW  = (unsigned short*)(R2 + (size_t)ROWS * THREE_D);
    unsigned short* pWo = pW + (size_t)THREE_D * D_MODEL * 2;
    float* tab = (float*)(pWo + (size_t)D_MODEL * D_MODEL * 2);

    unsigned short* px    = (unsigned short*)R1;   // dead once qkvp written
    unsigned short* qkvp  = (unsigned short*)R1;   // packed q/k/v (3 segments)
    unsigned short* pcomb = (unsigned short*)R2;
    unsigned short* pctx  = (unsigned short*)R2;   // overwrites pcomb (dead)

    unsigned short* Qp = qkvp;
    unsigned short* Kp = qkvp + (size_t)ROWS * D_MODEL * 2;
    unsigned short* Vp = Kp  + (size_t)ROWS * D_MODEL * 2;

    const dim3 blk(256);

    rope_table<<<dim3(SEQ * 32 / 256), blk, 0, stream>>>(tab);

    // pack inputs/weights to bf16 planes (one fused launch)
    split_pack3<<<dim3(4096), blk, 0, stream>>>(x, px, Win, pW, Wout, pWo);

    // GEMM1 + fused rope: pcomb = pack(rope(x @ Win^T + bin))
    gemm_p_rope<<<dim3(48, 32), blk, 0, stream>>>(
        px, D_MODEL * 2, pW, D_MODEL * 2, bin, tab, pcomb, D_MODEL);

    // fused q/k/v second projection -> PACKED planes (overwrites px; dead)
    gemm_p_pack<<<dim3(48, 32), blk, 0, stream>>>(
        pcomb, THREE_D * 2, pW, D_MODEL * 2, bin, qkvp, D_MODEL * 2, D_MODEL,
        16, (size_t)(D_MODEL * 2), (size_t)D_MODEL * D_MODEL * 2, D_MODEL,
        (size_t)ROWS * D_MODEL * 2);

    // attention on packed planes -> pctx (overwrites pcomb; dead)
    attn_mfma<<<dim3(SEQ / 128, BATCH * N_HEADS), dim3(512), 0, stream>>>(
        Qp, Kp, Vp, pctx);

    // GEMM3: out = ctx @ Wout^T + bout
    gemm_p<<<dim3(16, 32), blk, 0, stream>>>(
        pctx, D_MODEL * 2, pWo, D_MODEL * 2, bout, out, D_MODEL, D_MODEL,
        16, (size_t)0, (size_t)0, 0, (size_t)0);
}